// Round 16
// baseline (371.956 us; speedup 1.0000x reference)
//
#include <hip/hip_runtime.h>
#include <hip/hip_bf16.h>

// RGCN 2-layer + global mean pool + log_softmax. Round 32.
// R31's key-grouped layer-2 refactor was mathematically sound but had a
// mechanical bug: the hq epilogue wrote only words 0-3 of each row's 16
// uint words (lane -> word=lane&3), leaving channels 16-63 uninitialized
// -> absmax 5.5. R32 fix: each lane owns a row-QUARTER (row=lane>>2,
// qt=lane&3) and writes 4 uints (one uint4, channels qt*16..qt*16+15):
// 64 lanes x 4 uints = full 16x64 tile, 16B/lane coalesced. Also guard
// hsum tail rows. Everything else = R31 exact. Structure recap:
//   T_r[c] = sum_{keys (r,dst)} inv[k] * sum_{e in k} hq_src[c]
// via a second gather pass over the SAME rowptr/perm; removes kappa buffer,
// 1.6M-atomic drain, kred, and bf16 h entirely.

#define CH 64
#define BK_EDGES 2048
#define CAP 12288   // per-bucket record capacity (avg ~8163, >40 sigma)
#define RPT 12      // records per thread in build = CAP/1024

typedef __attribute__((ext_vector_type(8))) short short8;
typedef __attribute__((ext_vector_type(4))) float f32x4;
typedef __attribute__((ext_vector_type(2))) float f32x2;

__device__ inline ushort f2bf(float f) {
    unsigned b = __float_as_uint(f);
    unsigned r = (b + 0x7FFFu + ((b >> 16) & 1u)) >> 16;
    return (ushort)r;
}
__device__ inline float bf2f(ushort u) {
    return __uint_as_float(((unsigned)u) << 16);
}

// accumulate 8 fp8 channels (one uint2 = 8 bytes) into a[0..7] with mask m
__device__ inline void acc8fp8(float* a, uint2 w, float m) {
    f32x2 p;
    p = __builtin_amdgcn_cvt_pk_f32_fp8(w.x, 0); a[0] += m * p.x; a[1] += m * p.y;
    p = __builtin_amdgcn_cvt_pk_f32_fp8(w.x, 1); a[2] += m * p.x; a[3] += m * p.y;
    p = __builtin_amdgcn_cvt_pk_f32_fp8(w.y, 0); a[4] += m * p.x; a[5] += m * p.y;
    p = __builtin_amdgcn_cvt_pk_f32_fp8(w.y, 1); a[6] += m * p.x; a[7] += m * p.y;
}

// decode 8 fp8 bytes (uint2) -> bf16 short8 (for root A-frag)
__device__ inline short8 dec8fp8(uint2 w) {
    float f[8];
    f32x2 p;
    p = __builtin_amdgcn_cvt_pk_f32_fp8(w.x, 0); f[0] = p.x; f[1] = p.y;
    p = __builtin_amdgcn_cvt_pk_f32_fp8(w.x, 1); f[2] = p.x; f[3] = p.y;
    p = __builtin_amdgcn_cvt_pk_f32_fp8(w.y, 0); f[4] = p.x; f[5] = p.y;
    p = __builtin_amdgcn_cvt_pk_f32_fp8(w.y, 1); f[6] = p.x; f[7] = p.y;
    short8 r;
    #pragma unroll
    for (int k = 0; k < 8; ++k) r[k] = (short)f2bf(f[k]);
    return r;
}

// ---- prep: edge binning ONLY (copies live in build) ------------------------

__global__ __launch_bounds__(256) void prep_kernel(
    const int* __restrict__ src, const int* __restrict__ dst,
    const int* __restrict__ etype,
    int* __restrict__ gBucketCnt, int2* __restrict__ bucket_buf,
    int E, int N)
{
    __shared__ int s_k[BK_EDGES];
    __shared__ int s_y[BK_EDGES];
    __shared__ int hist[256], scanv[256], lcur[256], bstart[256], gbase[256];
    const int t = threadIdx.x;
    const int bid = blockIdx.x;

    const int e0 = bid * BK_EDGES;
    const int cnt = min(BK_EDGES, E - e0);

    hist[t] = 0;
    __syncthreads();

    int myb[8], myk[8], myy[8];
    #pragma unroll
    for (int i = 0; i < 8; ++i) {
        int li = t + i * 256;
        if (li < cnt) {
            int e = e0 + li;
            int r = etype[e];
            int k = r * N + dst[e];
            myk[i] = k;
            myy[i] = (r << 17) | src[e];
            myb[i] = k >> 12;
            atomicAdd(&hist[myb[i]], 1);
        } else myb[i] = -1;
    }
    __syncthreads();

    int v = hist[t];
    scanv[t] = v;
    __syncthreads();
    for (int off = 1; off < 256; off <<= 1) {
        int u = (t >= off) ? scanv[t - off] : 0;
        __syncthreads();
        scanv[t] += u;
        __syncthreads();
    }
    int excl = scanv[t] - v;
    bstart[t] = excl;
    lcur[t] = excl;
    __syncthreads();

    #pragma unroll
    for (int i = 0; i < 8; ++i) {
        if (myb[i] >= 0) {
            int p = atomicAdd(&lcur[myb[i]], 1);
            s_k[p] = myk[i];
            s_y[p] = myy[i];
        }
    }
    __syncthreads();

    if (v > 0) gbase[t] = atomicAdd(&gBucketCnt[t], v);
    __syncthreads();

    for (int p = t; p < cnt; p += 256) {
        int k = s_k[p];
        int b = k >> 12;
        int gp = gbase[b] + (p - bstart[b]);
        if (gp < CAP)
            bucket_buf[(size_t)b * CAP + gp] = make_int2(k, s_y[p]);
    }
}

// ---- build: blocks [0,nbuk): bucket sort (register build).
//      blocks [nbuk,..): xq copy (fp8) + wfrag swizzle. ---------------------

__global__ __launch_bounds__(1024) void build_kernel(
    const int2* __restrict__ bucket_buf, const int* __restrict__ gBucketCnt,
    int* __restrict__ rowptr, float* __restrict__ inv,
    int* __restrict__ perm,
    const float* __restrict__ x, const float* __restrict__ W1,
    const float* __restrict__ root1,
    unsigned char* __restrict__ xq, ushort* __restrict__ wf,
    int N, int nbuk, int nXbf)
{
    __shared__ int hist[4096];
    __shared__ int cur[4096];
    __shared__ int part[1024];
    const int t = threadIdx.x;
    const int bid = blockIdx.x;

    if (bid >= nbuk) {
        int cb = bid - nbuk;
        if (cb < nXbf) {                  // fp8 copy of x
            int i = cb * 1024 + t;
            if (i < N * CH / 4) {
                float4 v = ((const float4*)x)[i];
                int p8 = __builtin_amdgcn_cvt_pk_fp8_f32(v.x, v.y, 0, 0);
                p8 = __builtin_amdgcn_cvt_pk_fp8_f32(v.z, v.w, p8, 1);
                ((unsigned int*)xq)[i] = (unsigned int)p8;
            }
        } else {                          // weight B-fragment swizzle (9 mats)
            int idx = (cb - nXbf) * 1024 + t;
            if (idx < 9 * 2 * 4 * 64 * 8) {
                int j    = idx & 7;
                int lane = (idx >> 3) & 63;
                int ct   = (idx >> 9) & 3;
                int ks   = (idx >> 11) & 1;
                int rel  = idx >> 12;
                int k = ks * 32 + (lane >> 4) * 8 + j;
                int n = ct * 16 + (lane & 15);
                float v = (rel < 8) ? W1[((size_t)rel * 64 + k) * 64 + n]
                                    : root1[(size_t)k * 64 + n];
                wf[idx] = f2bf(v);
            }
        }
        return;
    }

    const int b = bid;
    const int nb = min(gBucketCnt[b], CAP);
    const int2* rec = bucket_buf + (size_t)b * CAP;

    int rk[RPT], ry[RPT];
    #pragma unroll
    for (int i = 0; i < RPT; ++i) {
        int j = t + i * 1024;
        if (j < nb) { int2 v = rec[j]; rk[i] = v.x; ry[i] = v.y; }
        else        { rk[i] = -1; ry[i] = 0; }
    }

    int bc = (t < 256) ? gBucketCnt[t] : 0;
    part[t] = bc;
    __syncthreads();
    for (int off = 1; off < 1024; off <<= 1) {
        int u = (t >= off) ? part[t - off] : 0;
        __syncthreads();
        part[t] += u;
        __syncthreads();
    }
    __shared__ int baseS;
    if (t == b) baseS = part[t] - bc;
    __syncthreads();
    const int base = baseS;

    for (int i = t; i < 4096; i += 1024) hist[i] = 0;
    __syncthreads();
    #pragma unroll
    for (int i = 0; i < RPT; ++i)
        if (rk[i] >= 0) atomicAdd(&hist[rk[i] & 4095], 1);
    __syncthreads();

    const int i0 = t * 4;
    int h0 = hist[i0], h1 = hist[i0 + 1], h2 = hist[i0 + 2], h3 = hist[i0 + 3];
    int s = h0 + h1 + h2 + h3;
    part[t] = s;
    __syncthreads();
    for (int off = 1; off < 1024; off <<= 1) {
        int u = (t >= off) ? part[t - off] : 0;
        __syncthreads();
        part[t] += u;
        __syncthreads();
    }
    int run = base + part[t] - s;
    int hk[4] = {h0, h1, h2, h3};
    #pragma unroll
    for (int k = 0; k < 4; ++k) {
        cur[i0 + k] = run;
        rowptr[b * 4096 + i0 + k] = run;
        inv[b * 4096 + i0 + k] = 1.0f / (float)max(hk[k], 1);
        run += hk[k];
    }
    __syncthreads();

    #pragma unroll
    for (int i = 0; i < RPT; ++i) {
        if (rk[i] >= 0) {
            int pos = atomicAdd(&cur[rk[i] & 4095], 1);
            perm[pos] = ry[i] & 0x1FFFF;
        }
    }
}

// ---- fused layer 1 (no kappa; epilogue: hq fp8 + per-block hsum) -----------

__global__ __launch_bounds__(256) void rgcn1_fused_kernel(
    const int* __restrict__ rowptr, const int* __restrict__ perm,
    const float* __restrict__ inv,
    const unsigned char* __restrict__ xq,
    const ushort* __restrict__ wfrag, const float* __restrict__ b1,
    unsigned char* __restrict__ hq, float* __restrict__ hsum_partial,
    int N)
{
    __shared__ ushort Abuf[4][16 * 72];   // MFMA A-tile; reused for epilogue
    __shared__ int    rpS[4][144];
    __shared__ float  invS[4][128];
    __shared__ float  hsumS[4][64];
    const int widx = threadIdx.x >> 6;
    const int lane = threadIdx.x & 63;
    const int wid = (blockIdx.x << 2) | widx;
    const int base = wid << 4;
    const bool active = base < N;        // NO early return (block barrier below)

    const int m0 = lane & 15;
    const int q  = lane >> 4;
    const int sg = lane >> 3;
    const int cg = lane & 7;
    ushort* ab = Abuf[widx];
    int*    rpL = rpS[widx];
    float*  ivL = invS[widx];

    f32x4 acc4[4];
    #pragma unroll
    for (int ct = 0; ct < 4; ++ct) acc4[ct] = (f32x4)(0.0f);

    if (active) {
        for (int i = lane; i < 136; i += 64) {
            int r = i / 17, mm = i - r * 17;
            rpL[i] = rowptr[(size_t)r * N + base + mm];
        }
        for (int i = lane; i < 128; i += 64)
            ivL[i] = inv[(size_t)(i >> 4) * N + base + (i & 15)];

        for (int r = 0; r < 8; ++r) {
            const int iA = r * 17 + sg;
            const int iB = iA + 8;
            int jA = rpL[iA], eA = rpL[iA + 1];
            int jB = rpL[iB], eB = rpL[iB + 1];
            float a[8] = {}, bacc[8] = {};
            int s0A = perm[(jA     < eA) ? jA     : 0];
            int s1A = perm[(jA + 1 < eA) ? jA + 1 : 0];
            int s0B = perm[(jB     < eB) ? jB     : 0];
            int s1B = perm[(jB + 1 < eB) ? jB + 1 : 0];
            while (jA < eA || jB < eB) {
                uint2 w0A = *(const uint2*)(xq + (size_t)s0A * CH + (cg << 3));
                uint2 w1A = *(const uint2*)(xq + (size_t)s1A * CH + (cg << 3));
                uint2 w0B = *(const uint2*)(xq + (size_t)s0B * CH + (cg << 3));
                uint2 w1B = *(const uint2*)(xq + (size_t)s1B * CH + (cg << 3));
                int t0A = perm[(jA + 2 < eA) ? jA + 2 : 0];
                int t1A = perm[(jA + 3 < eA) ? jA + 3 : 0];
                int t0B = perm[(jB + 2 < eB) ? jB + 2 : 0];
                int t1B = perm[(jB + 3 < eB) ? jB + 3 : 0];
                float m0A = (jA     < eA) ? 1.f : 0.f;
                float m1A = (jA + 1 < eA) ? 1.f : 0.f;
                float m0B = (jB     < eB) ? 1.f : 0.f;
                float m1B = (jB + 1 < eB) ? 1.f : 0.f;
                acc8fp8(a,    w0A, m0A);
                acc8fp8(a,    w1A, m1A);
                acc8fp8(bacc, w0B, m0B);
                acc8fp8(bacc, w1B, m1B);
                s0A = t0A; s1A = t1A; s0B = t0B; s1B = t1B;
                jA += 2; jB += 2;
            }
            const float ivA = ivL[(r << 4) | sg];
            const float ivB = ivL[(r << 4) | (8 + sg)];
            short8 oA, oB;
            #pragma unroll
            for (int k = 0; k < 8; ++k) {
                oA[k] = (short)f2bf(a[k] * ivA);
                oB[k] = (short)f2bf(bacc[k] * ivB);
            }
            *(short8*)&ab[sg * 72 + (cg << 3)]       = oA;
            *(short8*)&ab[(8 + sg) * 72 + (cg << 3)] = oB;

            #pragma unroll
            for (int s = 0; s < 2; ++s) {
                short8 av = *(short8*)&ab[m0 * 72 + s * 32 + q * 8];
                #pragma unroll
                for (int ct = 0; ct < 4; ++ct) {
                    short8 bv = *(const short8*)&wfrag[(((size_t)(r * 2 + s) * 4 + ct) * 64 + lane) * 8];
                    acc4[ct] = __builtin_amdgcn_mfma_f32_16x16x32_bf16(av, bv, acc4[ct], 0, 0, 0);
                }
            }
        }

        {   // root: A-frag decoded from fp8 xq (rel index 8 in wfrag)
            int node = min(base + m0, N - 1);
            #pragma unroll
            for (int s = 0; s < 2; ++s) {
                uint2 wv = *(const uint2*)(xq + (size_t)node * CH + s * 32 + q * 8);
                short8 av = dec8fp8(wv);
                #pragma unroll
                for (int ct = 0; ct < 4; ++ct) {
                    short8 bv = *(const short8*)&wfrag[(((size_t)(8 * 2 + s) * 4 + ct) * 64 + lane) * 8];
                    acc4[ct] = __builtin_amdgcn_mfma_f32_16x16x32_bf16(av, bv, acc4[ct], 0, 0, 0);
                }
            }
        }

        // write relu'd h tile (bf16) into ab, stride 64 (per-wave, prog order)
        // D[row=q*4+v][col=ct*16+m0]
        #pragma unroll
        for (int ct = 0; ct < 4; ++ct) {
            int c = ct * 16 + m0;
            float bb = b1[c];
            #pragma unroll
            for (int v = 0; v < 4; ++v)
                ab[(q * 4 + v) * 64 + c] = f2bf(fmaxf(acc4[ct][v] + bb, 0.f));
        }

        // hq packed write (FIXED): lane -> (row=lane>>2, quarter=lane&3);
        // each lane packs channels qt*16..qt*16+15 into a uint4 (16B store).
        // 64 lanes x 4 uints = full 16 rows x 16 words.
        {
            int row = lane >> 2, qt = lane & 3;
            if (base + row < N) {
                unsigned up[4];
                #pragma unroll
                for (int w = 0; w < 4; ++w) {
                    int c0 = qt * 16 + w * 4;
                    float f0 = bf2f(ab[row * 64 + c0 + 0]);
                    float f1 = bf2f(ab[row * 64 + c0 + 1]);
                    float f2 = bf2f(ab[row * 64 + c0 + 2]);
                    float f3 = bf2f(ab[row * 64 + c0 + 3]);
                    int u = __builtin_amdgcn_cvt_pk_fp8_f32(f0, f1, 0, 0);
                    u = __builtin_amdgcn_cvt_pk_fp8_f32(f2, f3, u, 1);
                    up[w] = (unsigned)u;
                }
                uint4 uv = make_uint4(up[0], up[1], up[2], up[3]);
                *(uint4*)&hq[(size_t)(base + row) * CH + qt * 16] = uv;
            }
        }
    }

    // per-block hsum partial (root2 term): wave column sums then cross-wave
    float s = 0.f;
    if (active) {
        #pragma unroll
        for (int row = 0; row < 16; ++row)
            if (base + row < N) s += bf2f(ab[row * 64 + lane]);
    }
    hsumS[widx][lane] = s;
    __syncthreads();
    if (widx == 0)
        hsum_partial[(size_t)blockIdx.x * 64 + lane] =
            hsumS[0][lane] + hsumS[1][lane] + hsumS[2][lane] + hsumS[3][lane];
}

// ---- layer 2 relation terms: gather pass over the SAME sorted structure ----
// T_r[c] += inv[key] * sum_{edges in key} hq[src][c]; per-wave racc[8][8],
// shuffle-reduced over sg, LDS-reduced over waves -> per-block partial.

__global__ __launch_bounds__(256) void rgcn2_gather_kernel(
    const int* __restrict__ rowptr, const int* __restrict__ perm,
    const float* __restrict__ inv, const unsigned char* __restrict__ hq,
    float* __restrict__ rel_partial, int N)
{
    __shared__ int    rpS[4][144];
    __shared__ float  invS[4][128];
    __shared__ float  relS[4][512];
    const int widx = threadIdx.x >> 6;
    const int lane = threadIdx.x & 63;
    const int wid = (blockIdx.x << 2) | widx;
    const int base = wid << 4;
    const bool active = base < N;        // NO early return

    const int sg = lane >> 3;
    const int cg = lane & 7;
    int*   rpL = rpS[widx];
    float* ivL = invS[widx];

    float racc[8][8];
    #pragma unroll
    for (int r = 0; r < 8; ++r)
        #pragma unroll
        for (int k = 0; k < 8; ++k) racc[r][k] = 0.f;

    if (active) {
        for (int i = lane; i < 136; i += 64) {
            int r = i / 17, mm = i - r * 17;
            rpL[i] = rowptr[(size_t)r * N + base + mm];
        }
        for (int i = lane; i < 128; i += 64)
            ivL[i] = inv[(size_t)(i >> 4) * N + base + (i & 15)];

        #pragma unroll
        for (int r = 0; r < 8; ++r) {
            const int iA = r * 17 + sg;
            const int iB = iA + 8;
            int jA = rpL[iA], eA = rpL[iA + 1];
            int jB = rpL[iB], eB = rpL[iB + 1];
            float a[8] = {}, bacc[8] = {};
            int s0A = perm[(jA     < eA) ? jA     : 0];
            int s1A = perm[(jA + 1 < eA) ? jA + 1 : 0];
            int s0B = perm[(jB     < eB) ? jB     : 0];
            int s1B = perm[(jB + 1 < eB) ? jB + 1 : 0];
            while (jA < eA || jB < eB) {
                uint2 w0A = *(const uint2*)(hq + (size_t)s0A * CH + (cg << 3));
                uint2 w1A = *(const uint2*)(hq + (size_t)s1A * CH + (cg << 3));
                uint2 w0B = *(const uint2*)(hq + (size_t)s0B * CH + (cg << 3));
                uint2 w1B = *(const uint2*)(hq + (size_t)s1B * CH + (cg << 3));
                int t0A = perm[(jA + 2 < eA) ? jA + 2 : 0];
                int t1A = perm[(jA + 3 < eA) ? jA + 3 : 0];
                int t0B = perm[(jB + 2 < eB) ? jB + 2 : 0];
                int t1B = perm[(jB + 3 < eB) ? jB + 3 : 0];
                float m0A = (jA     < eA) ? 1.f : 0.f;
                float m1A = (jA + 1 < eA) ? 1.f : 0.f;
                float m0B = (jB     < eB) ? 1.f : 0.f;
                float m1B = (jB + 1 < eB) ? 1.f : 0.f;
                acc8fp8(a,    w0A, m0A);
                acc8fp8(a,    w1A, m1A);
                acc8fp8(bacc, w0B, m0B);
                acc8fp8(bacc, w1B, m1B);
                s0A = t0A; s1A = t1A; s0B = t0B; s1B = t1B;
                jA += 2; jB += 2;
            }
            const float ivA = ivL[(r << 4) | sg];
            const float ivB = ivL[(r << 4) | (8 + sg)];
            #pragma unroll
            for (int k = 0; k < 8; ++k)
                racc[r][k] += ivA * a[k] + ivB * bacc[k];
        }
    }

    // reduce over sg (lanes sharing cg): 3 xor-shuffles; sg==0 lanes write
    #pragma unroll
    for (int r = 0; r < 8; ++r) {
        #pragma unroll
        for (int k = 0; k < 8; ++k) {
            float v = racc[r][k];
            v += __shfl_xor(v, 8);
            v += __shfl_xor(v, 16);
            v += __shfl_xor(v, 32);
            if (sg == 0) relS[widx][r * 64 + cg * 8 + k] = v;
        }
    }
    __syncthreads();
    // cross-wave reduce + per-block partial store (512 floats)
    for (int idx = threadIdx.x; idx < 512; idx += 256) {
        float v = relS[0][idx] + relS[1][idx] + relS[2][idx] + relS[3][idx];
        rel_partial[(size_t)blockIdx.x * 512 + idx] = v;
    }
}

// ---- final reduce (rel + hsum partials) + fused finalize -------------------

__global__ __launch_bounds__(576) void kred2_kernel(
    const float* __restrict__ rel_partial, const float* __restrict__ hsum_partial,
    float* __restrict__ sacc, int* __restrict__ done,
    const float* __restrict__ root2, const float* __restrict__ W2,
    const float* __restrict__ b2, float* __restrict__ out,
    float invN, int nblk)
{
    const int j = threadIdx.x;               // 0..575
    const int chunk = (nblk + 7) >> 3;
    const int b0 = blockIdx.x * chunk;
    const int b1e = min(b0 + chunk, nblk);
    float s = 0.f;
    if (j < 512) {
        for (int b = b0; b < b1e; ++b) s += rel_partial[(size_t)b * 512 + j];
    } else {
        int c = j - 512;
        for (int b = b0; b < b1e; ++b) s += hsum_partial[(size_t)b * 64 + c];
    }
    unsafeAtomicAdd(&sacc[j], s);
    __threadfence();
    __syncthreads();
    __shared__ int tk;
    if (j == 0) tk = atomicAdd(done, 1);
    __syncthreads();
    if (tk != 7) return;
    __threadfence();

    __shared__ float g[16];
    if (j < 16) {
        const float* s0 = sacc + 512;
        float acc = 0.f;
        for (int c = 0; c < 64; ++c) acc += s0[c] * root2[c * 16 + j];
        for (int r = 0; r < 8; ++r) {
            const float* sr = sacc + r * 64;
            for (int c = 0; c < 64; ++c) acc += sr[c] * W2[(r * 64 + c) * 16 + j];
        }
        g[j] = acc * invN + b2[j];
    }
    __syncthreads();
    if (j < 16) {
        float m = -1e30f;
        for (int i = 0; i < 16; ++i) m = fmaxf(m, g[i]);
        float sm = 0.f;
        for (int i = 0; i < 16; ++i) sm += expf(g[i] - m);
        out[j] = g[j] - (m + logf(sm));
    }
}

// ---- launch -----------------------------------------------------------------

extern "C" void kernel_launch(void* const* d_in, const int* in_sizes, int n_in,
                              void* d_out, int out_size, void* d_ws, size_t ws_size,
                              hipStream_t stream)
{
    const float* x     = (const float*)d_in[0];
    const int*   eidx  = (const int*)d_in[1];
    const int*   etype = (const int*)d_in[2];
    const float* W1    = (const float*)d_in[3];
    const float* root1 = (const float*)d_in[4];
    const float* b1    = (const float*)d_in[5];
    const float* W2    = (const float*)d_in[6];
    const float* root2 = (const float*)d_in[7];
    const float* b2    = (const float*)d_in[8];
    float* out = (float*)d_out;

    const int E = in_sizes[1] / 2;
    const int N = in_sizes[0] / CH;
    const int NKEY = N * 8;
    const int NBUK = (NKEY + 4095) / 4096;         // 196 for N=100K (<=256)
    const int KSPACE = NBUK << 12;
    const int* srcI = eidx;
    const int* dstI = eidx + E;
    const int tiles = (N + 15) / 16;
    const int NBLK  = (tiles + 3) / 4;             // fused1/gather2 blocks

    // workspace layout (4B units):
    // [gBucketCnt 256 | sacc 576 | done 16]      <- zeroed by memset (3.4KB)
    // [inv KSPACE | rowptr KSPACE+16 | perm E | bucket_buf (8B-al) NBUK*CAP*2 |
    //  wfrag 18432 | xq N*CH/4 | hq N*CH/4 | rel_partial NBLK*512 |
    //  hsum_partial NBLK*64]
    int* wsi = (int*)d_ws;
    int*   gBucketCnt = wsi;
    float* sacc       = (float*)(gBucketCnt + 256);
    int*   done       = (int*)(sacc + 576);
    float* inv        = (float*)(done + 16);
    int*   rowptr     = (int*)(inv + KSPACE);
    int*   perm       = rowptr + KSPACE + 16;
    size_t off = (size_t)((perm + E) - wsi);
    off = (off + 1) & ~(size_t)1;                  // 8B-align
    int2*  bucket_buf = (int2*)(wsi + off);
    off += (size_t)NBUK * CAP * 2;
    off = (off + 7) & ~(size_t)7;                  // 32B-align
    ushort* wfg = (ushort*)(wsi + off);
    unsigned char* xq = (unsigned char*)(wfg + 36864);
    unsigned char* hq = xq + (size_t)N * CH;
    float* rel_partial  = (float*)(hq + (size_t)N * CH);
    float* hsum_partial = rel_partial + (size_t)NBLK * 512;

    hipMemsetAsync(d_ws, 0, (size_t)(256 + 576 + 16) * 4, stream);

    const int nBin = (E + BK_EDGES - 1) / BK_EDGES;
    prep_kernel<<<nBin, 256, 0, stream>>>(
        srcI, dstI, etype, gBucketCnt, bucket_buf, E, N);

    const int nXbf = (N * CH / 4 + 1023) / 1024;
    const int nWf  = (36864 + 1023) / 1024;
    build_kernel<<<NBUK + nXbf + nWf, 1024, 0, stream>>>(
        bucket_buf, gBucketCnt, rowptr, inv, perm,
        x, W1, root1, xq, wfg, N, NBUK, nXbf);

    rgcn1_fused_kernel<<<NBLK, 256, 0, stream>>>(
        rowptr, perm, inv, xq, wfg, b1, hq, hsum_partial, N);

    rgcn2_gather_kernel<<<NBLK, 256, 0, stream>>>(
        rowptr, perm, inv, hq, rel_partial, N);

    kred2_kernel<<<8, 576, 0, stream>>>(rel_partial, hsum_partial, sacc, done,
                                        root2, W2, b2, out,
                                        1.0f / (float)N, NBLK);
}

// Round 17
// 270.349 us; speedup vs baseline: 1.3758x; 1.3758x over previous
//
#include <hip/hip_runtime.h>
#include <hip/hip_bf16.h>

// RGCN 2-layer + global mean pool + log_softmax. Round 33 = R30 revert (best).
// R32 post-mortem: the key-grouped two-gather structure is strictly worse --
// gather2 alone = 102us (VGPR=100 -> occ 17.6%) and the edge traversal runs
// TWICE, with no atomic drain left to hide under it. R30 traverses edges
// once and hides the ~90us kappa-atomic drain (measured HW wall, ~17.8G
// atomics/s) under the gather. Final config (273.9us measured, absmax 0.0):
//  - prep: edge binning (block counting-sort by key>>12)
//  - build: register bucket sort + kappa zero + fp8 xq copy + wfrag swizzle
//  - fused: KB=128 kappa atomic blocks (fed from bucket_buf, inv L2-hot)
//           overlapped with per-wave 16-node-tile fp8 gather + MFMA;
//           root term from xq; h stored bf16
//  - kred: simple loop @1024 blocks -> partial[1024][576] (no sacc atomics)
//  - kred2: 8x576 column-sum + ticketed last-block finalize (fence cheap at 8)

#define CH 64
#define BK_EDGES 2048
#define CAP 12288   // per-bucket record capacity (avg ~8163, >40 sigma)
#define RPT 12      // records per thread in build = CAP/1024
#define KB 128      // dedicated kappa blocks at head of fused grid
#define KRB 1024    // kred blocks (partial rows)

typedef __attribute__((ext_vector_type(8))) short short8;
typedef __attribute__((ext_vector_type(4))) float f32x4;
typedef __attribute__((ext_vector_type(2))) float f32x2;

__device__ inline ushort f2bf(float f) {
    unsigned b = __float_as_uint(f);
    unsigned r = (b + 0x7FFFu + ((b >> 16) & 1u)) >> 16;
    return (ushort)r;
}
__device__ inline float bf2f(ushort u) {
    return __uint_as_float(((unsigned)u) << 16);
}

// accumulate 8 fp8 channels (one uint2 = 8 bytes) into a[0..7] with mask m
__device__ inline void acc8fp8(float* a, uint2 w, float m) {
    f32x2 p;
    p = __builtin_amdgcn_cvt_pk_f32_fp8(w.x, 0); a[0] += m * p.x; a[1] += m * p.y;
    p = __builtin_amdgcn_cvt_pk_f32_fp8(w.x, 1); a[2] += m * p.x; a[3] += m * p.y;
    p = __builtin_amdgcn_cvt_pk_f32_fp8(w.y, 0); a[4] += m * p.x; a[5] += m * p.y;
    p = __builtin_amdgcn_cvt_pk_f32_fp8(w.y, 1); a[6] += m * p.x; a[7] += m * p.y;
}

// decode 8 fp8 bytes (uint2) -> bf16 short8 (for root A-frag)
__device__ inline short8 dec8fp8(uint2 w) {
    float f[8];
    f32x2 p;
    p = __builtin_amdgcn_cvt_pk_f32_fp8(w.x, 0); f[0] = p.x; f[1] = p.y;
    p = __builtin_amdgcn_cvt_pk_f32_fp8(w.x, 1); f[2] = p.x; f[3] = p.y;
    p = __builtin_amdgcn_cvt_pk_f32_fp8(w.y, 0); f[4] = p.x; f[5] = p.y;
    p = __builtin_amdgcn_cvt_pk_f32_fp8(w.y, 1); f[6] = p.x; f[7] = p.y;
    short8 r;
    #pragma unroll
    for (int k = 0; k < 8; ++k) r[k] = (short)f2bf(f[k]);
    return r;
}

// ---- prep: edge binning ONLY (copies live in build) ------------------------

__global__ __launch_bounds__(256) void prep_kernel(
    const int* __restrict__ src, const int* __restrict__ dst,
    const int* __restrict__ etype,
    int* __restrict__ gBucketCnt, int2* __restrict__ bucket_buf,
    int E, int N)
{
    __shared__ int s_k[BK_EDGES];
    __shared__ int s_y[BK_EDGES];
    __shared__ int hist[256], scanv[256], lcur[256], bstart[256], gbase[256];
    const int t = threadIdx.x;
    const int bid = blockIdx.x;

    const int e0 = bid * BK_EDGES;
    const int cnt = min(BK_EDGES, E - e0);

    hist[t] = 0;
    __syncthreads();

    int myb[8], myk[8], myy[8];
    #pragma unroll
    for (int i = 0; i < 8; ++i) {
        int li = t + i * 256;
        if (li < cnt) {
            int e = e0 + li;
            int r = etype[e];
            int k = r * N + dst[e];
            myk[i] = k;
            myy[i] = (r << 17) | src[e];
            myb[i] = k >> 12;
            atomicAdd(&hist[myb[i]], 1);
        } else myb[i] = -1;
    }
    __syncthreads();

    int v = hist[t];
    scanv[t] = v;
    __syncthreads();
    for (int off = 1; off < 256; off <<= 1) {
        int u = (t >= off) ? scanv[t - off] : 0;
        __syncthreads();
        scanv[t] += u;
        __syncthreads();
    }
    int excl = scanv[t] - v;
    bstart[t] = excl;
    lcur[t] = excl;
    __syncthreads();

    #pragma unroll
    for (int i = 0; i < 8; ++i) {
        if (myb[i] >= 0) {
            int p = atomicAdd(&lcur[myb[i]], 1);
            s_k[p] = myk[i];
            s_y[p] = myy[i];
        }
    }
    __syncthreads();

    if (v > 0) gbase[t] = atomicAdd(&gBucketCnt[t], v);
    __syncthreads();

    for (int p = t; p < cnt; p += 256) {
        int k = s_k[p];
        int b = k >> 12;
        int gp = gbase[b] + (p - bstart[b]);
        if (gp < CAP)
            bucket_buf[(size_t)b * CAP + gp] = make_int2(k, s_y[p]);
    }
}

// ---- build: blocks [0,nbuk): bucket sort (register build) + kappa zero.
//      blocks [nbuk,..): xq copy (fp8 only). --------------------------------

__global__ __launch_bounds__(1024) void build_kernel(
    const int2* __restrict__ bucket_buf, const int* __restrict__ gBucketCnt,
    int* __restrict__ rowptr, float* __restrict__ inv,
    int* __restrict__ perm,
    const float* __restrict__ x, const float* __restrict__ W1,
    const float* __restrict__ root1,
    unsigned char* __restrict__ xq, ushort* __restrict__ wf,
    float* __restrict__ kappa, int nkey,
    int N, int nbuk, int nXbf)
{
    __shared__ int hist[4096];
    __shared__ int cur[4096];
    __shared__ int part[1024];
    const int t = threadIdx.x;
    const int bid = blockIdx.x;

    if (bid >= nbuk) {
        int cb = bid - nbuk;
        if (cb < nXbf) {                  // fp8 copy of x
            int i = cb * 1024 + t;
            if (i < N * CH / 4) {
                float4 v = ((const float4*)x)[i];
                int p8 = __builtin_amdgcn_cvt_pk_fp8_f32(v.x, v.y, 0, 0);
                p8 = __builtin_amdgcn_cvt_pk_fp8_f32(v.z, v.w, p8, 1);
                ((unsigned int*)xq)[i] = (unsigned int)p8;
            }
        } else {                          // weight B-fragment swizzle (9 mats)
            int idx = (cb - nXbf) * 1024 + t;
            if (idx < 9 * 2 * 4 * 64 * 8) {
                int j    = idx & 7;
                int lane = (idx >> 3) & 63;
                int ct   = (idx >> 9) & 3;
                int ks   = (idx >> 11) & 1;
                int rel  = idx >> 12;
                int k = ks * 32 + (lane >> 4) * 8 + j;
                int n = ct * 16 + (lane & 15);
                float v = (rel < 8) ? W1[((size_t)rel * 64 + k) * 64 + n]
                                    : root1[(size_t)k * 64 + n];
                wf[idx] = f2bf(v);
            }
        }
        return;
    }

    const int b = bid;
    const int nb = min(gBucketCnt[b], CAP);
    const int2* rec = bucket_buf + (size_t)b * CAP;

    // kappa zero (R25 algebra: -6us vs memset); consumer is the NEXT kernel
    for (int i = b * 1024 + t; i < nkey; i += nbuk * 1024)
        kappa[i] = 0.0f;

    // phase 1: all my records -> registers (static unroll, coalesced)
    int rk[RPT], ry[RPT];
    #pragma unroll
    for (int i = 0; i < RPT; ++i) {
        int j = t + i * 1024;
        if (j < nb) { int2 v = rec[j]; rk[i] = v.x; ry[i] = v.y; }
        else        { rk[i] = -1; ry[i] = 0; }
    }

    // bucket base = exclusive prefix of gBucketCnt (256 entries, zero-padded)
    int bc = (t < 256) ? gBucketCnt[t] : 0;
    part[t] = bc;
    __syncthreads();
    for (int off = 1; off < 1024; off <<= 1) {
        int u = (t >= off) ? part[t - off] : 0;
        __syncthreads();
        part[t] += u;
        __syncthreads();
    }
    __shared__ int baseS;
    if (t == b) baseS = part[t] - bc;
    __syncthreads();
    const int base = baseS;

    for (int i = t; i < 4096; i += 1024) hist[i] = 0;
    __syncthreads();
    #pragma unroll
    for (int i = 0; i < RPT; ++i)
        if (rk[i] >= 0) atomicAdd(&hist[rk[i] & 4095], 1);
    __syncthreads();

    const int i0 = t * 4;
    int h0 = hist[i0], h1 = hist[i0 + 1], h2 = hist[i0 + 2], h3 = hist[i0 + 3];
    int s = h0 + h1 + h2 + h3;
    part[t] = s;
    __syncthreads();
    for (int off = 1; off < 1024; off <<= 1) {
        int u = (t >= off) ? part[t - off] : 0;
        __syncthreads();
        part[t] += u;
        __syncthreads();
    }
    int run = base + part[t] - s;
    int hk[4] = {h0, h1, h2, h3};
    #pragma unroll
    for (int k = 0; k < 4; ++k) {
        cur[i0 + k] = run;
        rowptr[b * 4096 + i0 + k] = run;
        inv[b * 4096 + i0 + k] = 1.0f / (float)max(hk[k], 1);
        run += hk[k];
    }
    __syncthreads();

    // placement from registers: LDS cursor atomic + perm store (no loads)
    #pragma unroll
    for (int i = 0; i < RPT; ++i) {
        if (rk[i] >= 0) {
            int pos = atomicAdd(&cur[rk[i] & 4095], 1);
            perm[pos] = ry[i] & 0x1FFFF;
        }
    }
}

// ---- fused layer 1 + dedicated kappa blocks (root from xq) -----------------

__global__ __launch_bounds__(256) void rgcn1_fused_kernel(
    const int* __restrict__ rowptr, const int* __restrict__ perm,
    const float* __restrict__ inv,
    const unsigned char* __restrict__ xq,
    const ushort* __restrict__ wfrag, const float* __restrict__ b1,
    const int2* __restrict__ bucket_buf, const int* __restrict__ gBucketCnt,
    float* __restrict__ kappa,
    ushort* __restrict__ h, int N, int nbuk)
{
    if (blockIdx.x < KB) {
        // kappa-only block: records of buckets bid, bid+KB, ...
        for (int b = blockIdx.x; b < nbuk; b += KB) {
            const int nb = min(gBucketCnt[b], CAP);
            const int2* rec = bucket_buf + (size_t)b * CAP;
            for (int j = (int)threadIdx.x; j < nb; j += 256) {
                int2 v = rec[j];
                float iv = inv[v.x];       // key = r*N+dst, 16KB hot window
                unsafeAtomicAdd(&kappa[((v.y & 0x1FFFF) << 3) | (v.y >> 17)], iv);
            }
        }
        return;
    }

    __shared__ ushort Abuf[4][16 * 72];   // 16x64 bf16 A-tile, row stride 72
    __shared__ int    rpS[4][144];        // rowptr[r*N+base+mm], i = r*17+mm
    __shared__ float  invS[4][128];       // inv[r*N+base+m],     i = r*16+m
    const int widx = threadIdx.x >> 6;
    const int lane = threadIdx.x & 63;
    const int wid = ((blockIdx.x - KB) << 2) | widx;
    const int base = wid << 4;
    if (base >= N) return;

    const int m0 = lane & 15;
    const int q  = lane >> 4;
    const int sg = lane >> 3;
    const int cg = lane & 7;
    ushort* ab = Abuf[widx];
    int*    rpL = rpS[widx];
    float*  ivL = invS[widx];

    for (int i = lane; i < 136; i += 64) {
        int r = i / 17, mm = i - r * 17;
        rpL[i] = rowptr[(size_t)r * N + base + mm];
    }
    for (int i = lane; i < 128; i += 64)
        ivL[i] = inv[(size_t)(i >> 4) * N + base + (i & 15)];

    f32x4 acc4[4];
    #pragma unroll
    for (int ct = 0; ct < 4; ++ct) acc4[ct] = (f32x4)(0.0f);

    for (int r = 0; r < 8; ++r) {
        const int iA = r * 17 + sg;
        const int iB = iA + 8;
        int jA = rpL[iA], eA = rpL[iA + 1];
        int jB = rpL[iB], eB = rpL[iB + 1];
        float a[8] = {}, bacc[8] = {};
        int s0A = perm[(jA     < eA) ? jA     : 0];
        int s1A = perm[(jA + 1 < eA) ? jA + 1 : 0];
        int s0B = perm[(jB     < eB) ? jB     : 0];
        int s1B = perm[(jB + 1 < eB) ? jB + 1 : 0];
        while (jA < eA || jB < eB) {
            uint2 w0A = *(const uint2*)(xq + (size_t)s0A * CH + (cg << 3));
            uint2 w1A = *(const uint2*)(xq + (size_t)s1A * CH + (cg << 3));
            uint2 w0B = *(const uint2*)(xq + (size_t)s0B * CH + (cg << 3));
            uint2 w1B = *(const uint2*)(xq + (size_t)s1B * CH + (cg << 3));
            int t0A = perm[(jA + 2 < eA) ? jA + 2 : 0];   // prefetch next pair
            int t1A = perm[(jA + 3 < eA) ? jA + 3 : 0];
            int t0B = perm[(jB + 2 < eB) ? jB + 2 : 0];
            int t1B = perm[(jB + 3 < eB) ? jB + 3 : 0];
            float m0A = (jA     < eA) ? 1.f : 0.f;
            float m1A = (jA + 1 < eA) ? 1.f : 0.f;
            float m0B = (jB     < eB) ? 1.f : 0.f;
            float m1B = (jB + 1 < eB) ? 1.f : 0.f;
            acc8fp8(a,    w0A, m0A);
            acc8fp8(a,    w1A, m1A);
            acc8fp8(bacc, w0B, m0B);
            acc8fp8(bacc, w1B, m1B);
            s0A = t0A; s1A = t1A; s0B = t0B; s1B = t1B;
            jA += 2; jB += 2;
        }
        const float ivA = ivL[(r << 4) | sg];
        const float ivB = ivL[(r << 4) | (8 + sg)];
        short8 oA, oB;
        #pragma unroll
        for (int k = 0; k < 8; ++k) {
            oA[k] = (short)f2bf(a[k] * ivA);
            oB[k] = (short)f2bf(bacc[k] * ivB);
        }
        *(short8*)&ab[sg * 72 + (cg << 3)]       = oA;
        *(short8*)&ab[(8 + sg) * 72 + (cg << 3)] = oB;

        // MFMA: 2 K-steps x 4 col-tiles (per-wave LDS is program-ordered)
        #pragma unroll
        for (int s = 0; s < 2; ++s) {
            short8 av = *(short8*)&ab[m0 * 72 + s * 32 + q * 8];
            #pragma unroll
            for (int ct = 0; ct < 4; ++ct) {
                short8 bv = *(const short8*)&wfrag[(((size_t)(r * 2 + s) * 4 + ct) * 64 + lane) * 8];
                acc4[ct] = __builtin_amdgcn_mfma_f32_16x16x32_bf16(av, bv, acc4[ct], 0, 0, 0);
            }
        }
    }

    {   // root: A-frag decoded from fp8 xq (rel index 8 in wfrag)
        int node = min(base + m0, N - 1);
        #pragma unroll
        for (int s = 0; s < 2; ++s) {
            uint2 wv = *(const uint2*)(xq + (size_t)node * CH + s * 32 + q * 8);
            short8 av = dec8fp8(wv);
            #pragma unroll
            for (int ct = 0; ct < 4; ++ct) {
                short8 bv = *(const short8*)&wfrag[(((size_t)(8 * 2 + s) * 4 + ct) * 64 + lane) * 8];
                acc4[ct] = __builtin_amdgcn_mfma_f32_16x16x32_bf16(av, bv, acc4[ct], 0, 0, 0);
            }
        }
    }

    // epilogue: D[row=q*4+v][col=ct*16+m0], stored bf16 (kred-only consumer)
    #pragma unroll
    for (int ct = 0; ct < 4; ++ct) {
        int c = ct * 16 + m0;
        float bb = b1[c];
        #pragma unroll
        for (int v = 0; v < 4; ++v) {
            int node = base + q * 4 + v;
            if (node < N)
                h[(size_t)node * CH + c] = f2bf(fmaxf(acc4[ct][v] + bb, 0.f));
        }
    }
}

// ---- layer-2 collapse, stage 1: per-block partials, NO sacc atomics --------

__global__ __launch_bounds__(256) void kred_kernel(
    const ushort* __restrict__ h, const float* __restrict__ kappa,
    float* __restrict__ partial, int N)
{
    const int lane = threadIdx.x & 63;
    const int w = threadIdx.x >> 6;
    int wave = (blockIdx.x << 2) | w;
    const int wstride = gridDim.x << 2;
    float racc[9] = {};
    for (int i = wave; i < N; i += wstride) {
        float hv = bf2f(h[(size_t)i * CH + lane]);
        #pragma unroll
        for (int r = 0; r < 8; ++r) racc[r] += hv * kappa[i * 8 + r];
        racc[8] += hv;
    }
    __shared__ float red[4][9][64];
    #pragma unroll
    for (int r = 0; r < 9; ++r) red[w][r][lane] = racc[r];
    __syncthreads();
    if (w == 0) {
        #pragma unroll
        for (int r = 0; r < 9; ++r) {
            float s4 = red[0][r][lane] + red[1][r][lane] + red[2][r][lane] + red[3][r][lane];
            partial[(size_t)blockIdx.x * 576 + r * 64 + lane] = s4;
        }
    }
}

// ---- layer-2 collapse, stage 2: column-sum + fused finalize ----------------
// 8 blocks x 576 thr; 8 RMWs/address tail; LAST block (ticket, fence cost
// trivial at 8 blocks) computes the 16 outputs.

__global__ __launch_bounds__(576) void kred2_kernel(
    const float* __restrict__ partial, float* __restrict__ sacc,
    int* __restrict__ done,
    const float* __restrict__ root2, const float* __restrict__ W2,
    const float* __restrict__ b2, float* __restrict__ out,
    float invN, int nblk)
{
    const int j = threadIdx.x;               // 0..575
    const int chunk = nblk >> 3;
    const int b0 = blockIdx.x * chunk;
    float s = 0.f;
    for (int b = b0; b < b0 + chunk; b += 4) {
        float v0 = partial[(size_t)b * 576 + j];
        float v1 = partial[(size_t)(b + 1) * 576 + j];
        float v2 = partial[(size_t)(b + 2) * 576 + j];
        float v3 = partial[(size_t)(b + 3) * 576 + j];
        s += (v0 + v1) + (v2 + v3);
    }
    unsafeAtomicAdd(&sacc[j], s);
    __threadfence();
    __syncthreads();
    __shared__ int tk;
    if (j == 0) tk = atomicAdd(done, 1);
    __syncthreads();
    if (tk != 7) return;
    __threadfence();

    __shared__ float g[16];
    if (j < 16) {
        const float* s0 = sacc + 512;
        float acc = 0.f;
        for (int c = 0; c < 64; ++c) acc += s0[c] * root2[c * 16 + j];
        for (int r = 0; r < 8; ++r) {
            const float* sr = sacc + r * 64;
            for (int c = 0; c < 64; ++c) acc += sr[c] * W2[(r * 64 + c) * 16 + j];
        }
        g[j] = acc * invN + b2[j];
    }
    __syncthreads();
    if (j < 16) {
        float m = -1e30f;
        for (int i = 0; i < 16; ++i) m = fmaxf(m, g[i]);
        float sm = 0.f;
        for (int i = 0; i < 16; ++i) sm += expf(g[i] - m);
        out[j] = g[j] - (m + logf(sm));
    }
}

// ---- launch -----------------------------------------------------------------

extern "C" void kernel_launch(void* const* d_in, const int* in_sizes, int n_in,
                              void* d_out, int out_size, void* d_ws, size_t ws_size,
                              hipStream_t stream)
{
    const float* x     = (const float*)d_in[0];
    const int*   eidx  = (const int*)d_in[1];
    const int*   etype = (const int*)d_in[2];
    const float* W1    = (const float*)d_in[3];
    const float* root1 = (const float*)d_in[4];
    const float* b1    = (const float*)d_in[5];
    const float* W2    = (const float*)d_in[6];
    const float* root2 = (const float*)d_in[7];
    const float* b2    = (const float*)d_in[8];
    float* out = (float*)d_out;

    const int E = in_sizes[1] / 2;
    const int N = in_sizes[0] / CH;
    const int NKEY = N * 8;
    const int NBUK = (NKEY + 4095) / 4096;         // 196 for N=100K (<=256)
    const int KSPACE = NBUK << 12;
    const int* srcI = eidx;
    const int* dstI = eidx + E;

    // workspace layout (4B units):
    // [gBucketCnt 256 | sacc 576 | done 16]      <- zeroed by memset (3.4KB)
    // [kappa NKEY (zeroed by build) | inv KSPACE | rowptr KSPACE+16 | perm E |
    //  bucket_buf (8B-al) NBUK*CAP*2 | wfrag 18432 | xq N*CH/4 |
    //  h(bf16) N*CH/2 | partial KRB*576]
    int* wsi = (int*)d_ws;
    int*   gBucketCnt = wsi;
    float* sacc       = (float*)(gBucketCnt + 256);
    int*   done       = (int*)(sacc + 576);
    float* kappa      = (float*)(done + 16);
    float* inv        = kappa + NKEY;
    int*   rowptr     = (int*)(inv + KSPACE);
    int*   perm       = rowptr + KSPACE + 16;
    size_t off = (size_t)((perm + E) - wsi);
    off = (off + 1) & ~(size_t)1;                  // 8B-align
    int2*  bucket_buf = (int2*)(wsi + off);
    off += (size_t)NBUK * CAP * 2;
    off = (off + 7) & ~(size_t)7;                  // 32B-align
    ushort* wfg = (ushort*)(wsi + off);
    unsigned char* xq = (unsigned char*)(wfg + 36864);
    ushort* h = (ushort*)(xq + (size_t)N * CH);
    float* partial = (float*)(h + (size_t)N * CH);

    hipMemsetAsync(d_ws, 0, (size_t)(256 + 576 + 16) * 4, stream);

    const int nBin = (E + BK_EDGES - 1) / BK_EDGES;
    prep_kernel<<<nBin, 256, 0, stream>>>(
        srcI, dstI, etype, gBucketCnt, bucket_buf, E, N);

    const int nXbf = (N * CH / 4 + 1023) / 1024;
    const int nWf  = (36864 + 1023) / 1024;
    build_kernel<<<NBUK + nXbf + nWf, 1024, 0, stream>>>(
        bucket_buf, gBucketCnt, rowptr, inv, perm,
        x, W1, root1, xq, wfg, kappa, NKEY, N, NBUK, nXbf);

    const int tiles = (N + 15) / 16;
    rgcn1_fused_kernel<<<KB + (tiles + 3) / 4, 256, 0, stream>>>(
        rowptr, perm, inv, xq, wfg, b1, bucket_buf, gBucketCnt, kappa,
        h, N, NBUK);

    kred_kernel<<<KRB, 256, 0, stream>>>(h, kappa, partial, N);
    kred2_kernel<<<8, 576, 0, stream>>>(partial, sacc, done,
                                        root2, W2, b2, out,
                                        1.0f / (float)N, KRB);
}